// Round 7
// baseline (172.392 us; speedup 1.0000x reference)
//
#include <hip/hip_runtime.h>

// Depthwise xcorr: out[p][oy][ox] = sum_{ky,kx} x[p][oy+ky][ox+kx] * z[p][ky][kx]
// 32768 planes. x: 31x31, z: 7x7, out: 25x25, fp32.
//
// Round 7: issue/overlap-bound diagnosis. R6 regressed vs R5 purely from lane
// efficiency (200/256 vs 250/256) while conflicts proved non-critical.
// This round: 128-thread blocks, PPB=5 -> 125/128 lanes active (97.7%),
// LDS = x only (23040 B) -> 7 blocks/CU for fine stage/compute overlap,
// z loaded straight to regs from global (L1 broadcast, overlaps stage drain).
// Keep RS=37 conflict-free LDS layout staged via pre-swizzled global source.

#define PPB 5
#define WX 31
#define RS 37                   // LDS row stride (== 5 mod 32): conflict-free
#define XPLANE 961              // packed global plane
#define LDSPLANE (31 * RS)      // 1147
#define ZPLANE 49
#define OPLANE 625
#define WO 25
#define XFLOATS (PPB * LDSPLANE)           // 5735
#define XCHUNKS ((XFLOATS + 127) / 128)    // 45
#define XSLOTS (XCHUNKS * 128)             // 5760 floats = 23040 B

typedef __attribute__((address_space(1))) const void gaddr_t;
typedef __attribute__((address_space(3))) void laddr_t;

__global__ __launch_bounds__(128, 4) void dwxcorr_kernel(
    const float* __restrict__ z, const float* __restrict__ x,
    float* __restrict__ out, int nplanes) {
  __shared__ float xs[XSLOTS];  // 23040 B -> 7 blocks/CU

  const int tid = threadIdx.x;
  const int p0 = blockIdx.x * PPB;
  const int pmax = min(PPB, nplanes - p0);
  const long XTOT = (long)nplanes * XPLANE;
  const long xoff = (long)p0 * XPLANE;
  const int wbase = tid & ~63;  // wave-uniform LDS chunk base

  // ---- stage x: LDS linear, global source pre-swizzled (padded->packed) ----
  // padded slot s = c*128 + tid: pp = s/1147, r = (s%1147)/37, col = s%37
  {
    int pp = 0, rem = tid;  // tid < 128 < 1147
#pragma unroll
    for (int c = 0; c < XCHUNKS; ++c) {
      int ppc = pp, rr = rem;
      if (ppc >= PPB) { ppc = PPB - 1; rr = LDSPLANE - 1; }  // 25 overhang slots
      int r = rr / RS;
      int col = rr - r * RS;
      col = (col > 30) ? 30 : col;  // pad cols dup col 30 (never read)
      long gi = xoff + ppc * XPLANE + r * WX + col;
      if (gi >= XTOT) gi = XTOT - 1;  // tail-block clamp (dup, never read)
      __builtin_amdgcn_global_load_lds((gaddr_t*)(x + gi),
                                       (laddr_t*)&xs[c * 128 + wbase], 4, 0, 0);
      rem += 128;
      if (rem >= LDSPLANE) { rem -= LDSPLANE; pp++; }
    }
  }

  // ---- compute mapping; z -> regs from global BEFORE barrier (overlaps) ----
  const int cpp = tid / 25;               // plane within block (0..5)
  const int t25 = tid - cpp * 25;
  const int ty = t25 / 5;
  const int tx = t25 - ty * 5;
  const int zp = min(p0 + min(cpp, pmax - 1), nplanes - 1);  // clamped, safe
  const float* zb = z + (size_t)zp * ZPLANE;
  float zr[ZPLANE];
#pragma unroll
  for (int j = 0; j < ZPLANE; ++j) zr[j] = zb[j];

  __syncthreads();  // drains vmcnt (stage + z loads) then barrier

  if (tid >= PPB * 25 || cpp >= pmax) return;  // 3 idle lanes normally

  float acc[5][5];
#pragma unroll
  for (int r = 0; r < 5; ++r)
#pragma unroll
    for (int j = 0; j < 5; ++j) acc[r][j] = 0.0f;

  const float* xbase = &xs[cpp * LDSPLANE + (ty * 5) * RS + tx * 5];

  // Stream 11 patch rows; row iy feeds output rows orow = iy-ky in [0,4]
#pragma unroll
  for (int iy = 0; iy < 11; ++iy) {
    float xr[11];
#pragma unroll
    for (int k = 0; k < 11; ++k) xr[k] = xbase[iy * RS + k];
    const int ky_lo = (iy - 4 < 0) ? 0 : iy - 4;
    const int ky_hi = (iy < 6) ? iy : 6;
#pragma unroll
    for (int ky = 0; ky < 7; ++ky) {
      if (ky < ky_lo || ky > ky_hi) continue;  // compile-time folded
      const int orow = iy - ky;
#pragma unroll
      for (int kx = 0; kx < 7; ++kx) {
        const float zv = zr[ky * 7 + kx];
#pragma unroll
        for (int j = 0; j < 5; ++j)
          acc[orow][j] = fmaf(xr[kx + j], zv, acc[orow][j]);
      }
    }
  }

  // ---- write the 5x5 tile ----
  float* ob = out + (size_t)(p0 + cpp) * OPLANE + (ty * 5) * WO + tx * 5;
#pragma unroll
  for (int r = 0; r < 5; ++r)
#pragma unroll
    for (int j = 0; j < 5; ++j) ob[r * WO + j] = acc[r][j];
}

extern "C" void kernel_launch(void* const* d_in, const int* in_sizes, int n_in,
                              void* d_out, int out_size, void* d_ws, size_t ws_size,
                              hipStream_t stream) {
  const float* z = (const float*)d_in[0];  // [B,C,7,7]
  const float* x = (const float*)d_in[1];  // [B,C,31,31]
  float* out = (float*)d_out;              // [B,C,25,25]

  const int nplanes = in_sizes[0] / ZPLANE;      // 32768
  const int blocks = (nplanes + PPB - 1) / PPB;  // 6554

  hipLaunchKernelGGL(dwxcorr_kernel, dim3(blocks), dim3(128), 0, stream,
                     z, x, out, nplanes);
}